// Round 5
// baseline (67.093 us; speedup 1.0000x reference)
//
#include <hip/hip_runtime.h>
#include <hip/hip_bf16.h>
#include <float.h>
#include <limits.h>

#define FEAT       256
#define GAMMA_F    0.1f
#define EPS_F      1e-8f
#define KSEL       64        // BUDGET
#define NBUCK      8192      // 13-bit histogram of flipped-float keys
#define NREP       8         // histogram replicas (atomic chains 64 -> 8)
#define CAP        2048      // LDS compaction capacity (expected ~80 used)
#define NB2        64        // select_kernel blocks
#define CPW        4         // candidates per wave (ILP in score kernel)
#define ZWORDS     (NBUCK * NREP + 1)   // ghist + done ticket

// Monotonic float -> uint transform (ascending order preserved).
__device__ __forceinline__ unsigned key_of(float v) {
    unsigned u = __float_as_uint(v);
    return u ^ ((u >> 31) ? 0xFFFFFFFFu : 0x80000000u);
}

__device__ __forceinline__ bool comes_first(float va, int ia, float vb, int ib) {
    return (va > vb) || (va == vb && ia < ib);
}

// ---------------------------------------------------------------------------
// Kernel 1: edge scores, 4 candidates per 64-lane wave (4 independent 1 KB
// row-gathers in flight). ALSO zeroes the K2 workspace (replicated histograms
// + ticket) with one coalesced store per low-gtid thread -- the kernel
// boundary publishes these zeros to K2, killing the memset dispatch.
// NO contended global atomics here (round-3 lesson: ~400cy per same-address
// device atomic, serialized).
// ---------------------------------------------------------------------------
__global__ __launch_bounds__(256) void edge_score_kernel(
    const float* __restrict__ infl,
    const float* __restrict__ feats,
    const int*   __restrict__ cand,
    const float* __restrict__ inj,
    float*       __restrict__ scores,   // d_out + KSEL
    unsigned*    __restrict__ ws_zero,  // ZWORDS words to clear
    int num_cand)
{
    const int gtid = blockIdx.x * blockDim.x + threadIdx.x;
    if (gtid < ZWORDS) ws_zero[gtid] = 0u;   // fire-and-forget

    const int wave = gtid >> 6;
    const int lane = threadIdx.x & 63;
    const int base = wave * CPW;
    if (base >= num_cand) return;

    const float4 g = *reinterpret_cast<const float4*>(inj + lane * 4);
    float ng = g.x * g.x + g.y * g.y + g.z * g.z + g.w * g.w;
    #pragma unroll
    for (int off = 32; off > 0; off >>= 1) ng += __shfl_xor(ng, off);
    const float inj_n = fmaxf(sqrtf(ng), EPS_F);

    // Issue all 4 row loads (independent -> memory-level parallelism).
    float4 f0, f1, f2, f3;
    const int n_here = num_cand - base;   // >= 1
    {
        const int r0 = cand[base];
        const int r1 = (n_here > 1) ? cand[base + 1] : r0;
        const int r2 = (n_here > 2) ? cand[base + 2] : r0;
        const int r3 = (n_here > 3) ? cand[base + 3] : r0;
        f0 = *reinterpret_cast<const float4*>(feats + (size_t)r0 * FEAT + lane * 4);
        f1 = *reinterpret_cast<const float4*>(feats + (size_t)r1 * FEAT + lane * 4);
        f2 = *reinterpret_cast<const float4*>(feats + (size_t)r2 * FEAT + lane * 4);
        f3 = *reinterpret_cast<const float4*>(feats + (size_t)r3 * FEAT + lane * 4);
    }

    float dot0 = f0.x*g.x + f0.y*g.y + f0.z*g.z + f0.w*g.w;
    float nf0  = f0.x*f0.x + f0.y*f0.y + f0.z*f0.z + f0.w*f0.w;
    float dot1 = f1.x*g.x + f1.y*g.y + f1.z*g.z + f1.w*g.w;
    float nf1  = f1.x*f1.x + f1.y*f1.y + f1.z*f1.z + f1.w*f1.w;
    float dot2 = f2.x*g.x + f2.y*g.y + f2.z*g.z + f2.w*g.w;
    float nf2  = f2.x*f2.x + f2.y*f2.y + f2.z*f2.z + f2.w*f2.w;
    float dot3 = f3.x*g.x + f3.y*g.y + f3.z*g.z + f3.w*g.w;
    float nf3  = f3.x*f3.x + f3.y*f3.y + f3.z*f3.z + f3.w*f3.w;

    // 8 independent butterfly chains -> good ILP across the 6 steps.
    #pragma unroll
    for (int off = 32; off > 0; off >>= 1) {
        dot0 += __shfl_xor(dot0, off);  nf0 += __shfl_xor(nf0, off);
        dot1 += __shfl_xor(dot1, off);  nf1 += __shfl_xor(nf1, off);
        dot2 += __shfl_xor(dot2, off);  nf2 += __shfl_xor(nf2, off);
        dot3 += __shfl_xor(dot3, off);  nf3 += __shfl_xor(nf3, off);
    }

    if (lane == 0) {
        scores[base] = infl[base] - GAMMA_F * (dot0 / (fmaxf(sqrtf(nf0), EPS_F) * inj_n));
        if (n_here > 1)
            scores[base+1] = infl[base+1] - GAMMA_F * (dot1 / (fmaxf(sqrtf(nf1), EPS_F) * inj_n));
        if (n_here > 2)
            scores[base+2] = infl[base+2] - GAMMA_F * (dot2 / (fmaxf(sqrtf(nf2), EPS_F) * inj_n));
        if (n_here > 3)
            scores[base+3] = infl[base+3] - GAMMA_F * (dot3 / (fmaxf(sqrtf(nf3), EPS_F) * inj_n));
    }
}

// ---------------------------------------------------------------------------
// Kernel 2: fused histogram + threshold + compact + top-64, 64 blocks.
//  A. per-block LDS histogram of scores (float4 reads);
//  B. merge nonzero buckets into replica blockIdx&7 of ghist[b][8]
//     (same-address device-atomic chains <= 8);
//  C. last-finished block (device ticket): suffix-scan summed replicas for
//     threshold bucket B, solo-compact survivors into LDS (LDS atomics only),
//     256-slot bitonic sort (value desc, index asc), write indices.
// ---------------------------------------------------------------------------
__global__ __launch_bounds__(256) void select_kernel(
    const float*    __restrict__ scores,
    unsigned*       __restrict__ ghist,   // [NBUCK][NREP]
    unsigned*       __restrict__ done,
    const int*      __restrict__ cand,
    float*          __restrict__ out,     // d_out[0..KSEL)
    int n)
{
    __shared__ unsigned h[NBUCK];
    __shared__ unsigned csum[256];
    __shared__ unsigned sB, sCnt;
    __shared__ int      sLast;
    __shared__ float    sv[CAP];
    __shared__ int      si[CAP];

    const int t   = threadIdx.x;
    const int bid = blockIdx.x;

    // --- A. LDS histogram ---
    for (int i = t; i < NBUCK; i += 256) h[i] = 0;
    __syncthreads();

    const int n4 = n >> 2;                 // n is a multiple of 4 here; tail below
    const float4* s4 = reinterpret_cast<const float4*>(scores);
    for (int g = bid * 256 + t; g < n4; g += NB2 * 256) {
        const float4 v = s4[g];
        atomicAdd(&h[key_of(v.x) >> 19], 1u);
        atomicAdd(&h[key_of(v.y) >> 19], 1u);
        atomicAdd(&h[key_of(v.z) >> 19], 1u);
        atomicAdd(&h[key_of(v.w) >> 19], 1u);
    }
    if (bid == 0 && t < (n & 3)) atomicAdd(&h[key_of(scores[n4 * 4 + t]) >> 19], 1u);
    __syncthreads();

    // --- B. merge into replica ---
    const int rep = bid & (NREP - 1);
    for (int b = t; b < NBUCK; b += 256)
        if (h[b]) atomicAdd(&ghist[b * NREP + rep], h[b]);

    // --- ticket: last block proceeds ---
    __threadfence();
    __syncthreads();
    if (t == 0) sLast = (atomicAdd(done, 1u) == (unsigned)(NB2 - 1));
    __syncthreads();
    if (!sLast) return;
    __threadfence();

    // --- C1. suffix-scan for threshold bucket B ---
    {
        const int hi = NBUCK - 32 * t;     // chunk t = buckets [hi-32, hi)
        unsigned s = 0;
        for (int b = hi - 32; b < hi; ++b) {
            const uint4 a0 = *reinterpret_cast<const uint4*>(&ghist[b * NREP]);
            const uint4 a1 = *reinterpret_cast<const uint4*>(&ghist[b * NREP + 4]);
            s += a0.x + a0.y + a0.z + a0.w + a1.x + a1.y + a1.z + a1.w;
        }
        csum[t] = s;
    }
    __syncthreads();
    if (t == 0) {
        unsigned cum = 0;
        int tc = 0;
        for (; tc < 256; ++tc) {
            if (cum + csum[tc] >= KSEL) break;
            cum += csum[tc];
        }
        unsigned B = 0;
        if (tc < 256) {
            int b = NBUCK - 32 * tc - 1;
            for (int k = 0; k < 32; ++k, --b) {
                unsigned cb = 0;
                #pragma unroll
                for (int r = 0; r < NREP; ++r) cb += ghist[b * NREP + r];
                cum += cb;
                if (cum >= KSEL) { B = (unsigned)b; break; }
            }
        }
        sB = B;
        sCnt = 0;
    }
    __syncthreads();
    const unsigned B = sB;

    // --- C2. solo compact into LDS (no global atomics) ---
    for (int g = t; g < n4; g += 256) {
        const float4 v = s4[g];
        const float vv[4] = {v.x, v.y, v.z, v.w};
        #pragma unroll
        for (int j = 0; j < 4; ++j) {
            if ((key_of(vv[j]) >> 19) >= B) {
                const unsigned p = atomicAdd(&sCnt, 1u);
                if (p < CAP) { sv[p] = vv[j]; si[p] = g * 4 + j; }
            }
        }
    }
    if (t < (n & 3)) {
        const float v = scores[n4 * 4 + t];
        if ((key_of(v) >> 19) >= B) {
            const unsigned p = atomicAdd(&sCnt, 1u);
            if (p < CAP) { sv[p] = v; si[p] = n4 * 4 + t; }
        }
    }
    __syncthreads();
    const int m = (int)min(sCnt, (unsigned)CAP);

    if (m <= 256) {
        // bitonic sort of 256 slots: value desc, index asc (lax.top_k order)
        if (t >= m) { sv[t] = -INFINITY; si[t] = INT_MAX; }
        __syncthreads();
        for (int k = 2; k <= 256; k <<= 1) {
            for (int j = k >> 1; j > 0; j >>= 1) {
                const int p = t ^ j;
                if (p > t) {
                    const float va = sv[t], vb = sv[p];
                    const int   ia = si[t], ib = si[p];
                    const bool asc = ((t & k) == 0);
                    const bool doSwap = asc ? comes_first(vb, ib, va, ia)
                                            : comes_first(va, ia, vb, ib);
                    if (doSwap) { sv[t] = vb; si[t] = ib; sv[p] = va; si[p] = ia; }
                }
                __syncthreads();
            }
        }
        if (t < KSEL) out[t] = (float)cand[si[t]];
        return;
    }

    // Fallback (never expected): serial argmax over m <= CAP survivors.
    __shared__ float wv[4];
    __shared__ int   wbi[4], wbs[4];
    for (int i = t + m; i < CAP; i += 256) { sv[i] = -INFINITY; si[i] = INT_MAX; }
    __syncthreads();
    for (int k = 0; k < KSEL; ++k) {
        float bv = -INFINITY; int bi = INT_MAX; int bs = 0;
        for (int i = t; i < CAP; i += 256) {
            if (comes_first(sv[i], si[i], bv, bi)) { bv = sv[i]; bi = si[i]; bs = i; }
        }
        #pragma unroll
        for (int off = 32; off > 0; off >>= 1) {
            const float ov = __shfl_xor(bv, off);
            const int   oi = __shfl_xor(bi, off);
            const int   os = __shfl_xor(bs, off);
            if (comes_first(ov, oi, bv, bi)) { bv = ov; bi = oi; bs = os; }
        }
        const int w = t >> 6;
        if ((t & 63) == 0) { wv[w] = bv; wbi[w] = bi; wbs[w] = bs; }
        __syncthreads();
        if (t == 0) {
            float fv = wv[0]; int fi = wbi[0]; int fs = wbs[0];
            #pragma unroll
            for (int j = 1; j < 4; ++j)
                if (comes_first(wv[j], wbi[j], fv, fi)) { fv = wv[j]; fi = wbi[j]; fs = wbs[j]; }
            out[k] = (float)cand[fi];
            sv[fs] = -INFINITY;
            si[fs] = INT_MAX;
        }
        __syncthreads();
    }
}

extern "C" void kernel_launch(void* const* d_in, const int* in_sizes, int n_in,
                              void* d_out, int out_size, void* d_ws, size_t ws_size,
                              hipStream_t stream) {
    const float* infl  = (const float*)d_in[0];   // [num_cand]
    const float* feats = (const float*)d_in[1];   // [num_nodes, 256]
    const int*   cand  = (const int*)d_in[2];     // [num_cand]
    const float* inj   = (const float*)d_in[3];   // [256]

    const int num_cand = in_sizes[0];

    float* out    = (float*)d_out;          // [0..64): indices-as-f32
    float* scores = (float*)d_out + KSEL;   // [64..64+num_cand): edge scores

    unsigned* ws_ghist = (unsigned*)d_ws;              // NBUCK*NREP
    unsigned* ws_done  = ws_ghist + NBUCK * NREP;      // 1

    // 1. Edge scores (+ workspace zeroing): 4 candidates per wave.
    {
        const int waves  = (num_cand + CPW - 1) / CPW;
        const int blocks = (waves + 3) / 4;
        edge_score_kernel<<<blocks, 256, 0, stream>>>(
            infl, feats, cand, inj, scores, ws_ghist, num_cand);
    }

    // 2. Fused histogram + threshold + compact + top-64.
    select_kernel<<<NB2, 256, 0, stream>>>(
        scores, ws_ghist, ws_done, cand, out, num_cand);
}

// Round 6
// 46.235 us; speedup vs baseline: 1.4511x; 1.4511x over previous
//
#include <hip/hip_runtime.h>
#include <hip/hip_bf16.h>
#include <float.h>
#include <limits.h>

#define FEAT       256
#define GAMMA_F    0.1f
#define EPS_F      1e-8f
#define KSEL       64        // BUDGET
#define NBUCK      4096      // 12-bit histogram of flipped-float keys
#define KSHIFT     20        // key >> KSHIFT -> bucket
#define NB1        1024      // persistent score blocks (4096 waves = full occupancy)
#define NB3        64        // hist/select blocks
#define CPW        4         // candidates per wave
#define BCAP       64        // per-block survivor region (expected ~2 used)
#define CAP        4096      // final assembly capacity (= NB3 * BCAP)
#define ZWORDS     (NBUCK + NB3 + 3)   // ghist + counts + done + oflow + oflowCnt

// Monotonic float -> uint transform (ascending order preserved).
__device__ __forceinline__ unsigned key_of(float v) {
    unsigned u = __float_as_uint(v);
    return u ^ ((u >> 31) ? 0xFFFFFFFFu : 0x80000000u);
}

__device__ __forceinline__ bool comes_first(float va, int ia, float vb, int ib) {
    return (va > vb) || (va == vb && ia < ib);
}

// ---------------------------------------------------------------------------
// Kernel 1: edge scores. PERSISTENT grid (1024 blocks = 4096 waves, exactly
// full occupancy at this VGPR count): each wave grid-strides over groups of
// CPW=4 candidates, keeping 4 KB of independent row-gathers in flight per
// iteration; ~3 iterations per wave keeps the VMEM pipe continuously fed
// (round-5 lesson: 12500 one-shot blocks churned too fast to hide ~900cy HBM
// latency). ||inj|| reduced once per wave before the loop. Lane 0 stores the
// 4 scores as one float4. Also zeroes the K2/K3 workspace (kills the memset
// node). NO contended atomics (round-3 lesson).
// ---------------------------------------------------------------------------
__global__ __launch_bounds__(256) void edge_score_kernel(
    const float* __restrict__ infl,
    const float* __restrict__ feats,
    const int*   __restrict__ cand,
    const float* __restrict__ inj,
    float*       __restrict__ scores,   // d_out + KSEL
    unsigned*    __restrict__ ws_zero,  // ZWORDS words to clear
    int num_cand)
{
    const int gtid = blockIdx.x * blockDim.x + threadIdx.x;
    if (gtid < ZWORDS) ws_zero[gtid] = 0u;   // fire-and-forget

    const int lane    = threadIdx.x & 63;
    const int wid     = gtid >> 6;              // global wave id
    const int nwaves  = NB1 * 4;
    const int ngroups = (num_cand + CPW - 1) / CPW;

    const float4 g = *reinterpret_cast<const float4*>(inj + lane * 4);
    float ng = g.x * g.x + g.y * g.y + g.z * g.z + g.w * g.w;
    #pragma unroll
    for (int off = 32; off > 0; off >>= 1) ng += __shfl_xor(ng, off);
    const float inj_n = fmaxf(sqrtf(ng), EPS_F);

    for (int grp = wid; grp < ngroups; grp += nwaves) {
        const int base   = grp * CPW;
        const int n_here = num_cand - base;   // >= 1

        const int r0 = cand[base];
        const int r1 = (n_here > 1) ? cand[base + 1] : r0;
        const int r2 = (n_here > 2) ? cand[base + 2] : r0;
        const int r3 = (n_here > 3) ? cand[base + 3] : r0;
        const float4 f0 = *reinterpret_cast<const float4*>(feats + (size_t)r0 * FEAT + lane * 4);
        const float4 f1 = *reinterpret_cast<const float4*>(feats + (size_t)r1 * FEAT + lane * 4);
        const float4 f2 = *reinterpret_cast<const float4*>(feats + (size_t)r2 * FEAT + lane * 4);
        const float4 f3 = *reinterpret_cast<const float4*>(feats + (size_t)r3 * FEAT + lane * 4);

        float dot0 = f0.x*g.x + f0.y*g.y + f0.z*g.z + f0.w*g.w;
        float nf0  = f0.x*f0.x + f0.y*f0.y + f0.z*f0.z + f0.w*f0.w;
        float dot1 = f1.x*g.x + f1.y*g.y + f1.z*g.z + f1.w*g.w;
        float nf1  = f1.x*f1.x + f1.y*f1.y + f1.z*f1.z + f1.w*f1.w;
        float dot2 = f2.x*g.x + f2.y*g.y + f2.z*g.z + f2.w*g.w;
        float nf2  = f2.x*f2.x + f2.y*f2.y + f2.z*f2.z + f2.w*f2.w;
        float dot3 = f3.x*g.x + f3.y*g.y + f3.z*g.z + f3.w*g.w;
        float nf3  = f3.x*f3.x + f3.y*f3.y + f3.z*f3.z + f3.w*f3.w;

        #pragma unroll
        for (int off = 32; off > 0; off >>= 1) {
            dot0 += __shfl_xor(dot0, off);  nf0 += __shfl_xor(nf0, off);
            dot1 += __shfl_xor(dot1, off);  nf1 += __shfl_xor(nf1, off);
            dot2 += __shfl_xor(dot2, off);  nf2 += __shfl_xor(nf2, off);
            dot3 += __shfl_xor(dot3, off);  nf3 += __shfl_xor(nf3, off);
        }

        if (lane == 0) {
            const float s0 = infl[base] - GAMMA_F * (dot0 / (fmaxf(sqrtf(nf0), EPS_F) * inj_n));
            if (n_here >= 4) {
                const float s1 = infl[base+1] - GAMMA_F * (dot1 / (fmaxf(sqrtf(nf1), EPS_F) * inj_n));
                const float s2 = infl[base+2] - GAMMA_F * (dot2 / (fmaxf(sqrtf(nf2), EPS_F) * inj_n));
                const float s3 = infl[base+3] - GAMMA_F * (dot3 / (fmaxf(sqrtf(nf3), EPS_F) * inj_n));
                *reinterpret_cast<float4*>(scores + base) = make_float4(s0, s1, s2, s3);
            } else {
                scores[base] = s0;
                if (n_here > 1)
                    scores[base+1] = infl[base+1] - GAMMA_F * (dot1 / (fmaxf(sqrtf(nf1), EPS_F) * inj_n));
                if (n_here > 2)
                    scores[base+2] = infl[base+2] - GAMMA_F * (dot2 / (fmaxf(sqrtf(nf2), EPS_F) * inj_n));
            }
        }
    }
}

// ---------------------------------------------------------------------------
// Kernel 2: 12-bit histogram. LDS pre-aggregation per block, then merge
// nonzero buckets (<=NB3 same-address global atomics, arrivals staggered).
// ---------------------------------------------------------------------------
__global__ __launch_bounds__(256) void hist_kernel(
    const float* __restrict__ scores,
    unsigned*    __restrict__ hist,
    int n)
{
    __shared__ unsigned h[NBUCK];
    for (int i = threadIdx.x; i < NBUCK; i += 256) h[i] = 0;
    __syncthreads();

    const int n4 = n >> 2;
    const float4* s4 = reinterpret_cast<const float4*>(scores);
    for (int g = blockIdx.x * 256 + threadIdx.x; g < n4; g += NB3 * 256) {
        const float4 v = s4[g];
        atomicAdd(&h[key_of(v.x) >> KSHIFT], 1u);
        atomicAdd(&h[key_of(v.y) >> KSHIFT], 1u);
        atomicAdd(&h[key_of(v.z) >> KSHIFT], 1u);
        atomicAdd(&h[key_of(v.w) >> KSHIFT], 1u);
    }
    if (blockIdx.x == 0 && threadIdx.x < (n & 3))
        atomicAdd(&h[key_of(scores[n4 * 4 + threadIdx.x]) >> KSHIFT], 1u);
    __syncthreads();

    for (int i = threadIdx.x; i < NBUCK; i += 256)
        if (h[i]) atomicAdd(&hist[i], h[i]);
}

// ---------------------------------------------------------------------------
// Kernel 3: select. Each block redundantly computes threshold bucket B
// (suffix-scan of the 16 KB L2-hot histogram), compacts its grid-stride
// slice's survivors into a PRIVATE 64-slot region (plain stores + one count
// store -- zero contended return-atomics; round-4 lesson). Last-finished
// block (ticket) prefix-sums the 64 counts, assembles survivors in LDS, and
// bitonic-sorts 256 slots (value desc, index asc) for the exact top-64.
// ---------------------------------------------------------------------------
__global__ __launch_bounds__(256) void select_kernel(
    const float*    __restrict__ scores,
    const unsigned* __restrict__ hist,
    unsigned*       __restrict__ counts,    // [NB3]
    unsigned*       __restrict__ done,
    unsigned*       __restrict__ oflow,     // flag + spill counter (2 words)
    float*          __restrict__ ws_v,      // [NB3*BCAP]
    int*            __restrict__ ws_i,      // [NB3*BCAP]
    const int*      __restrict__ cand,
    float*          __restrict__ out,       // d_out[0..KSEL)
    int n)
{
    __shared__ unsigned csum[256];
    __shared__ unsigned sB, sCnt;
    __shared__ int      sLast;
    __shared__ unsigned soff[NB3 + 1];
    __shared__ float    sv[CAP];
    __shared__ int      si[CAP];

    const int t   = threadIdx.x;
    const int bid = blockIdx.x;

    // --- 1. threshold bucket B (redundant per block; hist is L2-hot) ---
    {
        const int hi = NBUCK - 16 * t;     // chunk t = buckets [hi-16, hi)
        unsigned s = 0;
        for (int b = hi - 16; b < hi; ++b) s += hist[b];
        csum[t] = s;
    }
    __syncthreads();
    if (t == 0) {
        unsigned cum = 0;
        int tc = 0;
        for (; tc < 256; ++tc) {
            if (cum + csum[tc] >= KSEL) break;
            cum += csum[tc];
        }
        unsigned B = 0;
        if (tc < 256) {
            int b = NBUCK - 16 * tc - 1;
            for (int k = 0; k < 16; ++k, --b) {
                cum += hist[b];
                if (cum >= KSEL) { B = (unsigned)b; break; }
            }
        }
        sB = B;
        sCnt = 0;
    }
    __syncthreads();
    const unsigned B = sB;

    // --- 2. compact slice survivors into the block's private region ---
    const int n4 = n >> 2;
    const float4* s4 = reinterpret_cast<const float4*>(scores);
    for (int g = bid * 256 + t; g < n4; g += NB3 * 256) {
        const float4 v = s4[g];
        const float vv[4] = {v.x, v.y, v.z, v.w};
        #pragma unroll
        for (int j = 0; j < 4; ++j) {
            if ((key_of(vv[j]) >> KSHIFT) >= B) {
                const unsigned p = atomicAdd(&sCnt, 1u);   // LDS atomic
                if (p < BCAP) { ws_v[bid * BCAP + p] = vv[j]; ws_i[bid * BCAP + p] = g * 4 + j; }
            }
        }
    }
    if (bid == 0 && t < (n & 3)) {
        const float v = scores[n4 * 4 + t];
        if ((key_of(v) >> KSHIFT) >= B) {
            const unsigned p = atomicAdd(&sCnt, 1u);
            if (p < BCAP) { ws_v[p] = v; ws_i[p] = n4 * 4 + t; }
        }
    }
    __syncthreads();
    if (t == 0) {
        counts[bid] = min(sCnt, (unsigned)BCAP);
        if (sCnt > BCAP) atomicAdd(&oflow[0], 1u);   // never expected
    }

    // --- ticket: last-finished block assembles + sorts ---
    __threadfence();
    __syncthreads();
    if (t == 0) sLast = (atomicAdd(done, 1u) == (unsigned)(NB3 - 1));
    __syncthreads();
    if (!sLast) return;
    __threadfence();

    int m;
    if (oflow[0] == 0u) {
        // prefix offsets over the 64 region counts
        if (t == 0) {
            unsigned acc = 0;
            #pragma unroll
            for (int r = 0; r < NB3; ++r) { soff[r] = acc; acc += counts[r]; }
            soff[NB3] = acc;
        }
        __syncthreads();
        m = (int)soff[NB3];
        for (int idx = t; idx < NB3 * BCAP; idx += 256) {
            const int r = idx >> 6, j = idx & (BCAP - 1);
            if ((unsigned)j < counts[r]) {
                const unsigned dst = soff[r] + j;
                sv[dst] = ws_v[r * BCAP + j];
                si[dst] = ws_i[r * BCAP + j];
            }
        }
    } else {
        // Safety fallback: solo re-compact into LDS (never expected).
        if (t == 0) sCnt = 0;
        __syncthreads();
        for (int g = t; g < n; g += 256) {
            const float v = scores[g];
            if ((key_of(v) >> KSHIFT) >= B) {
                const unsigned p = atomicAdd(&sCnt, 1u);
                if (p < CAP) { sv[p] = v; si[p] = g; }
            }
        }
        __syncthreads();
        m = (int)min(sCnt, (unsigned)CAP);
    }
    __syncthreads();

    if (m <= 256) {
        // bitonic sort of 256 slots: value desc, index asc (lax.top_k order)
        if (t >= m) { sv[t] = -INFINITY; si[t] = INT_MAX; }
        __syncthreads();
        for (int k = 2; k <= 256; k <<= 1) {
            for (int j = k >> 1; j > 0; j >>= 1) {
                const int p = t ^ j;
                if (p > t) {
                    const float va = sv[t], vb = sv[p];
                    const int   ia = si[t], ib = si[p];
                    const bool asc = ((t & k) == 0);
                    const bool doSwap = asc ? comes_first(vb, ib, va, ia)
                                            : comes_first(va, ia, vb, ib);
                    if (doSwap) { sv[t] = vb; si[t] = ib; sv[p] = va; si[p] = ia; }
                }
                __syncthreads();
            }
        }
        if (t < KSEL) out[t] = (float)cand[si[t]];
        return;
    }

    // Fallback: serial argmax over m <= CAP survivors (never expected).
    __shared__ float wv[4];
    __shared__ int   wbi[4], wbs[4];
    for (int i = t + m; i < CAP; i += 256) { sv[i] = -INFINITY; si[i] = INT_MAX; }
    __syncthreads();
    for (int k = 0; k < KSEL; ++k) {
        float bv = -INFINITY; int bi = INT_MAX; int bs = 0;
        for (int i = t; i < CAP; i += 256) {
            if (comes_first(sv[i], si[i], bv, bi)) { bv = sv[i]; bi = si[i]; bs = i; }
        }
        #pragma unroll
        for (int off = 32; off > 0; off >>= 1) {
            const float ov = __shfl_xor(bv, off);
            const int   oi = __shfl_xor(bi, off);
            const int   os = __shfl_xor(bs, off);
            if (comes_first(ov, oi, bv, bi)) { bv = ov; bi = oi; bs = os; }
        }
        const int w = t >> 6;
        if ((t & 63) == 0) { wv[w] = bv; wbi[w] = bi; wbs[w] = bs; }
        __syncthreads();
        if (t == 0) {
            float fv = wv[0]; int fi = wbi[0]; int fs = wbs[0];
            #pragma unroll
            for (int j = 1; j < 4; ++j)
                if (comes_first(wv[j], wbi[j], fv, fi)) { fv = wv[j]; fi = wbi[j]; fs = wbs[j]; }
            out[k] = (float)cand[fi];
            sv[fs] = -INFINITY;
            si[fs] = INT_MAX;
        }
        __syncthreads();
    }
}

extern "C" void kernel_launch(void* const* d_in, const int* in_sizes, int n_in,
                              void* d_out, int out_size, void* d_ws, size_t ws_size,
                              hipStream_t stream) {
    const float* infl  = (const float*)d_in[0];   // [num_cand]
    const float* feats = (const float*)d_in[1];   // [num_nodes, 256]
    const int*   cand  = (const int*)d_in[2];     // [num_cand]
    const float* inj   = (const float*)d_in[3];   // [256]

    const int num_cand = in_sizes[0];

    float* out    = (float*)d_out;          // [0..64): indices-as-f32
    float* scores = (float*)d_out + KSEL;   // [64..64+num_cand): edge scores

    unsigned* ws_hist   = (unsigned*)d_ws;            // NBUCK
    unsigned* ws_counts = ws_hist + NBUCK;            // NB3
    unsigned* ws_done   = ws_counts + NB3;            // 1
    unsigned* ws_oflow  = ws_done + 1;                // 2
    float*    ws_v      = (float*)(ws_oflow + 2);     // NB3*BCAP
    int*      ws_i      = (int*)(ws_v + NB3 * BCAP);  // NB3*BCAP

    // 1. Edge scores (persistent grid) + workspace zeroing.
    edge_score_kernel<<<NB1, 256, 0, stream>>>(
        infl, feats, cand, inj, scores, ws_hist, num_cand);

    // 2. Histogram (LDS pre-aggregated).
    hist_kernel<<<NB3, 256, 0, stream>>>(scores, ws_hist, num_cand);

    // 3. Threshold + contention-free compact + final top-64.
    select_kernel<<<NB3, 256, 0, stream>>>(
        scores, ws_hist, ws_counts, ws_done, ws_oflow, ws_v, ws_i, cand, out, num_cand);
}